// Round 15
// baseline (2198.959 us; speedup 1.0000x reference)
//
#include <hip/hip_runtime.h>
#include <stdint.h>

#define B_   128
#define T_   128
#define D_   2048
#define H_   512
#define G3   1536
#define CH   1024
#define KC   512
#define OUTD 2048
#define IND  5120
#define TP   168
#define MPAD 144

typedef short vb8 __attribute__((ext_vector_type(8)));
typedef float v4f __attribute__((ext_vector_type(4)));

__device__ __forceinline__ unsigned short f2b(float f) {
  unsigned u = __float_as_uint(f);
  u = (u + 0x7FFFu + ((u >> 16) & 1u)) >> 16;
  return (unsigned short)u;
}
__device__ __forceinline__ float b2f(unsigned short u) {
  return __uint_as_float((unsigned)u << 16);
}

__device__ __forceinline__ void gl16(const unsigned short* g, unsigned short* l) {
  __builtin_amdgcn_global_load_lds(
      (const __attribute__((address_space(1))) void*)g,
      (__attribute__((address_space(3))) void*)l, 16, 0, 0);
}

// ---------------- f32 -> bf16 elementwise ----------------
__global__ void k_cvt(const float* __restrict__ in, unsigned short* __restrict__ out, int n4) {
  int stride = gridDim.x * blockDim.x;
  for (int i = blockIdx.x * blockDim.x + threadIdx.x; i < n4; i += stride) {
    float4 v = reinterpret_cast<const float4*>(in)[i];
    ushort4 o;
    o.x = f2b(v.x); o.y = f2b(v.y); o.z = f2b(v.z); o.w = f2b(v.w);
    reinterpret_cast<ushort4*>(out)[i] = o;
  }
}

// ---------------- fc_w [5120][2048] f32 -> [2048][5120] bf16 ----------------
__global__ void k_tcvt(const float* __restrict__ in, unsigned short* __restrict__ out) {
  __shared__ float tile[32][33];
  const int tx = threadIdx.x & 31;
  const int ty = threadIdx.x >> 5; // 0..7
  const int n0 = blockIdx.x * 32;
  const int k0 = blockIdx.y * 32;
#pragma unroll
  for (int i = 0; i < 4; ++i)
    tile[ty + 8 * i][tx] = in[(size_t)(k0 + ty + 8 * i) * OUTD + n0 + tx];
  __syncthreads();
#pragma unroll
  for (int i = 0; i < 4; ++i)
    out[(size_t)(n0 + ty + 8 * i) * IND + k0 + tx] = f2b(tile[tx][ty + 8 * i]);
}

// ---------------- bf16 MFMA GEMM, BK=64, global_load_lds staging ----------------
// C[m][n] = sum_k A[m][k] * Bm[n][k]  (+bias[n])
// K-tile = 64, two independent [128][32] LDS half-tiles per operand.
// EPI==0: linear store (CB: 1=bf16, 0=f32).
// EPI==1: merged conv epilogue (z=conv idx; relu + max over tau, atomicMax).
// EPI==2: merged-xw store: col<1536 -> fwd plane, else bwd plane (bf16).
// EPI==3: fc split-K: z=K-chunk; store raw acc to plane z (f32, no bias).
template<int EPI, int CB>
__global__ __launch_bounds__(256) void k_gemm(
    const unsigned short* __restrict__ A,
    const unsigned short* __restrict__ Bm,
    const float* __restrict__ bias,
    void* __restrict__ Cv,
    int K, int lda, int ldc, int convw)
{
  __shared__ unsigned short sA[2 * 128 * 32];   // halves at +0, +4096
  __shared__ unsigned short sB[2 * 128 * 32];
  float*          C32 = (float*)Cv;
  unsigned short* C16 = (unsigned short*)Cv;

  const int m0 = blockIdx.x * 128;
  const int n0 = blockIdx.y * 128;
  const int cz = blockIdx.z;

  // per-z parameters for merged conv / split-K fc
  int K_ = K;
  int w_ = convw;
  int koff = 0;
  const unsigned short* Bm_ = Bm;
  const float* bias_ = bias;
  if (EPI == 1) {
    constexpr int cum[4] = {0, 2, 5, 9};
    w_   = cz + 2;
    K_   = w_ * CH;
    Bm_  = Bm + (size_t)cum[cz] * KC * CH;
    bias_ = bias + cz * KC;
  } else if (EPI == 3) {
    koff = cz * K;          // K = chunk size; convw = B row stride (full K)
  }
  const int bstride = (EPI == 3) ? convw : K_;

  const int tid  = threadIdx.x;
  const int lane = tid & 63;
  const int wv   = tid >> 6;
  const int wr   = wv >> 1;
  const int wc   = wv & 1;

  const unsigned short* ag[2];
  const unsigned short* bg[2];
  unsigned short* al[2];
  unsigned short* bl[2];
#pragma unroll
  for (int q = 0; q < 2; ++q) {
    int c  = wv * 2 + q;
    int r  = c * 16 + (lane >> 2);
    int kc = (lane & 3) * 8;
    long abase;
    if (EPI == 1) {
      int m   = m0 + r;
      int b   = m / MPAD;
      int tau = m - b * MPAD;
      abase = (long)(b * TP + 4 + tau - (w_ - 1)) * CH;
    } else {
      abase = (long)(m0 + r) * lda + koff;
    }
    ag[q] = A + abase + kc;
    bg[q] = Bm_ + (long)(n0 + r) * bstride + kc + koff;
    al[q] = sA + c * 512;
    bl[q] = sB + c * 512;
  }

  v4f acc[4][4] = {};
  const int kq = (lane >> 4) * 8;
  const int fr = lane & 15;

  for (int k0 = 0; k0 < K_; k0 += 64) {
    if (k0) __syncthreads();
#pragma unroll
    for (int q = 0; q < 2; ++q) {
      gl16(ag[q] + k0,      al[q]);          // half 0
      gl16(ag[q] + k0 + 32, al[q] + 4096);   // half 1
      gl16(bg[q] + k0,      bl[q]);
      gl16(bg[q] + k0 + 32, bl[q] + 4096);
    }
    __syncthreads();
#pragma unroll
    for (int kk = 0; kk < 2; ++kk) {
      const int hb = kk * 4096;
      vb8 af[4], bfr[4];
#pragma unroll
      for (int i = 0; i < 4; ++i) {
        af[i]  = *reinterpret_cast<const vb8*>(sA + hb + (wr * 64 + i * 16 + fr) * 32 + kq);
        bfr[i] = *reinterpret_cast<const vb8*>(sB + hb + (wc * 64 + i * 16 + fr) * 32 + kq);
      }
#pragma unroll
      for (int i = 0; i < 4; ++i)
#pragma unroll
        for (int j = 0; j < 4; ++j)
          acc[i][j] = __builtin_amdgcn_mfma_f32_16x16x32_bf16(af[i], bfr[j], acc[i][j], 0, 0, 0);
    }
  }

  const int rl = lane >> 4;
#pragma unroll
  for (int i = 0; i < 4; ++i) {
#pragma unroll
    for (int j = 0; j < 4; ++j) {
      int col = n0 + wc * 64 + j * 16 + fr;
      float bs = (EPI == 3) ? 0.f : bias_[col];
      if (EPI == 0) {
#pragma unroll
        for (int r = 0; r < 4; ++r) {
          int m = m0 + wr * 64 + i * 16 + rl * 4 + r;
          float v = acc[i][j][r] + bs;
          if (CB) C16[(long)m * ldc + col] = f2b(v);
          else    C32[(long)m * ldc + col] = v;
        }
      } else if (EPI == 2) {
        const int dirb = col >= G3;
        const int xcol = col - dirb * G3;
        unsigned short* base = C16 + (size_t)dirb * ((size_t)B_ * T_ * G3);
#pragma unroll
        for (int r = 0; r < 4; ++r) {
          int m = m0 + wr * 64 + i * 16 + rl * 4 + r;
          base[(long)m * G3 + xcol] = f2b(acc[i][j][r] + bs);
        }
      } else if (EPI == 3) {
#pragma unroll
        for (int r = 0; r < 4; ++r) {
          int m = m0 + wr * 64 + i * 16 + rl * 4 + r;
          C32[(size_t)cz * (B_ * OUTD) + (long)m * ldc + col] = acc[i][j][r];
        }
      } else {
        int mf = m0 + wr * 64 + i * 16;   // 16 | 144 so single b per fragment
        int b  = mf / MPAD;
        int tf = mf - b * MPAD;
        float mx = 0.f;
#pragma unroll
        for (int r = 0; r < 4; ++r) {
          int tau = tf + rl * 4 + r;
          float v = acc[i][j][r] + bs;
          v = v > 0.f ? v : 0.f;
          if (tau < T_ + w_ - 1) mx = v > mx ? v : mx;
        }
        mx = fmaxf(mx, __shfl_xor(mx, 16));
        mx = fmaxf(mx, __shfl_xor(mx, 32));
        if (rl == 0 && tf < T_ + w_ - 1)
          atomicMax(reinterpret_cast<int*>(C32 + (long)b * ldc + cz * KC + col),
                    __float_as_int(mx));
      }
    }
  }
}

// ---------------- persistent bidirectional GRU scan (remap + incr. addressing) ----------------
// 32 WGs x 512 thr (16/dir), each owns 32 hidden units for ALL 128 batches.
// W_hh slice (96x512) in LDS, XOR-swizzled, loaded once. Wave (mg,jh): mg=wv&3
// owns 32 batches, jh=wv>>2 owns 16 units x 3 gates -> each W-frag feeds 2 MFMAs
// (W-LDS traffic halved vs r5; conflict-halving verified r7). All per-step
// addresses kept in registers and advanced incrementally (+-G3 / +-CH).
// Flag barrier (r14): release fence + per-WG flag, 16-lane parallel poll,
// one acquire fence. xw prefetched pre-barrier (r5-proven placement).
__global__ __launch_bounds__(512) void k_scan(
    const unsigned short* __restrict__ whh16,   // [2][1536][512] bf16
    const float* __restrict__ bhhf, const float* __restrict__ bhhb,
    const unsigned short* __restrict__ xw,      // [2][B][T][1536] bf16
    const int* __restrict__ lengths,
    unsigned short* __restrict__ hbuf,          // [2][2][128][512] bf16
    unsigned short* __restrict__ xpad,
    float* __restrict__ meang,
    unsigned int* __restrict__ flags)           // [2][16] flags, 64B apart
{
  __shared__ unsigned short sw[96 * 512];       // 96 KB, XOR-swizzled rows
  const int wg   = blockIdx.x;                  // 0..31
  const int dir  = wg >> 4;
  const int u0   = (wg & 15) * 32;
  const int tid  = threadIdx.x;                 // 0..511
  const int lane = tid & 63;
  const int wv   = tid >> 6;                    // 0..7
  const int mg   = wv & 3;                      // M-group (32 batches)
  const int jh   = wv >> 2;                     // unit half (16 units)
  const int fr   = lane & 15;
  const int rl   = lane >> 4;
  const int kq   = rl * 8;

  const unsigned short* Wd  = whh16 + (size_t)dir * (3 * H_ * H_);
  const float*          bhh = dir ? bhhb : bhhf;
  const unsigned short* xwd = xw + (size_t)dir * ((size_t)B_ * T_ * G3);
  unsigned short* hb = hbuf + dir * (2 * B_ * H_);
  unsigned int* myflags = flags + dir * 16 * 16;  // 16 flags, 64B apart

  // stage W slice: LDS row q = g*32+du  <->  W row g*512 + u0 + du ; swizzle ^((q&7)<<4)
  for (int i = tid; i < 96 * 64; i += 512) {
    int row  = i >> 6;
    int slot = i & 63;
    const unsigned short* src = Wd + (size_t)((row >> 5) * H_ + u0 + (row & 31)) * H_ + slot * 8;
    *reinterpret_cast<vb8*>((char*)sw + ((row * 1024 + slot * 16) ^ ((row & 7) << 4))) =
        *reinterpret_cast<const vb8*>(src);
  }
  __syncthreads();

  const int u  = u0 + jh * 16 + fr;
  const int t0 = dir ? (T_ - 1) : 0;
  const int xstep = dir ? -G3 : G3;             // xw offset delta per step
  const int pstep = dir ? -CH : CH;             // xpad offset delta per step

  int mylen[8];
  int hoff[8], poff[8];
#pragma unroll
  for (int mt = 0; mt < 2; ++mt)
#pragma unroll
    for (int r = 0; r < 4; ++r) {
      const int idx = mt * 4 + r;
      const int b   = mg * 32 + mt * 16 + rl * 4 + r;
      mylen[idx] = lengths[b];
      hoff[idx]  = b * H_ + u;
      poff[idx]  = (b * TP + 4 + t0) * CH + dir * H_ + u;
    }

  int xoff[3][2][4];
#pragma unroll
  for (int g = 0; g < 3; ++g)
#pragma unroll
    for (int mt = 0; mt < 2; ++mt)
#pragma unroll
      for (int r = 0; r < 4; ++r) {
        const int b = mg * 32 + mt * 16 + rl * 4 + r;
        xoff[g][mt][r] = (b * T_ + t0) * G3 + g * H_ + u;
      }

  int ab[2];
#pragma unroll
  for (int mt = 0; mt < 2; ++mt) ab[mt] = (mg * 32 + mt * 16 + fr) * H_ + kq;

  float bh[3];
#pragma unroll
  for (int g = 0; g < 3; ++g) bh[g] = bhh[g * H_ + u];

  float hst[8], macc[8];
#pragma unroll
  for (int i = 0; i < 8; ++i) { hst[i] = 0.f; macc[i] = 0.f; }

  // step-0 xw gates
  unsigned short uxw[3][2][4];
#pragma unroll
  for (int g = 0; g < 3; ++g)
#pragma unroll
    for (int mt = 0; mt < 2; ++mt)
#pragma unroll
      for (int r = 0; r < 4; ++r)
        uxw[g][mt][r] = xwd[xoff[g][mt][r]];

  for (int s = 0; s < T_; ++s) {
    const int t = dir ? (T_ - 1 - s) : s;

    v4f acc[2][3] = {};
    if (s > 0) {
      const unsigned short* hp = hb + ((s - 1) & 1) * (B_ * H_);
#pragma unroll 4
      for (int ks = 0; ks < 16; ++ks) {
        vb8 a0 = *reinterpret_cast<const vb8*>(hp + ab[0] + ks * 32);
        vb8 a1 = *reinterpret_cast<const vb8*>(hp + ab[1] + ks * 32);
#pragma unroll
        for (int g = 0; g < 3; ++g) {
          const int row = g * 32 + jh * 16 + fr;
          vb8 wf = *reinterpret_cast<const vb8*>(
              (const char*)sw + (((row * 1024) + ks * 64 + rl * 16) ^ ((row & 7) << 4)));
          acc[0][g] = __builtin_amdgcn_mfma_f32_16x16x32_bf16(a0, wf, acc[0][g], 0, 0, 0);
          acc[1][g] = __builtin_amdgcn_mfma_f32_16x16x32_bf16(a1, wf, acc[1][g], 0, 0, 0);
        }
      }
    }

    unsigned short* hc = hb + (s & 1) * (B_ * H_);
#pragma unroll
    for (int mt = 0; mt < 2; ++mt)
#pragma unroll
      for (int r = 0; r < 4; ++r) {
        const int idx = mt * 4 + r;
        float xr = b2f(uxw[0][mt][r]), xz = b2f(uxw[1][mt][r]), xn = b2f(uxw[2][mt][r]);
        float hr = acc[mt][0][r] + bh[0];
        float hz = acc[mt][1][r] + bh[1];
        float hn = acc[mt][2][r] + bh[2];
        float rr = 1.f / (1.f + __expf(-(xr + hr)));
        float z  = 1.f / (1.f + __expf(-(xz + hz)));
        float ax = xn + rr * hn;
        float n  = 2.f / (1.f + __expf(-2.f * ax)) - 1.f;
        float h  = (1.f - z) * n + z * hst[idx];
        hst[idx] = h;
        hc[hoff[idx]] = f2b(h);
        if (t < mylen[idx]) {
          xpad[poff[idx]] = f2b(h);
          macc[idx] += h;
        }
        poff[idx] += pstep;
      }

    if (s < T_ - 1) {
      // prefetch next step's xw (incremental offsets; drains during barrier spin)
#pragma unroll
      for (int g = 0; g < 3; ++g)
#pragma unroll
        for (int mt = 0; mt < 2; ++mt)
#pragma unroll
          for (int r = 0; r < 4; ++r) {
            xoff[g][mt][r] += xstep;
            uxw[g][mt][r] = xwd[xoff[g][mt][r]];
          }
      __syncthreads();                 // all waves' h-stores drained to L2
      if (tid == 0) {
        __builtin_amdgcn_fence(__ATOMIC_RELEASE, "agent");   // wbL2: publish h
        __hip_atomic_store(&myflags[(wg & 15) * 16], (unsigned)(s + 1),
                           __ATOMIC_RELAXED, __HIP_MEMORY_SCOPE_AGENT);
      }
      if (tid < 16) {                  // 16 lanes poll 16 flags in parallel
        while (__hip_atomic_load(&myflags[tid * 16], __ATOMIC_RELAXED,
                                 __HIP_MEMORY_SCOPE_AGENT) < (unsigned)(s + 1))
          __builtin_amdgcn_s_sleep(1);
      }
      if (tid == 0)
        __builtin_amdgcn_fence(__ATOMIC_ACQUIRE, "agent");   // one L1/L2 invalidate
      __syncthreads();
    }
  }

#pragma unroll
  for (int mt = 0; mt < 2; ++mt)
#pragma unroll
    for (int r = 0; r < 4; ++r) {
      const int idx = mt * 4 + r;
      const int b   = mg * 32 + mt * 16 + rl * 4 + r;
      meang[(size_t)b * CH + dir * H_ + u] = macc[idx] / (float)mylen[idx];
    }
}

// ---------------- feats assembly [128][5120] bf16 ----------------
__global__ void k_feats(const float* __restrict__ mg, const float* __restrict__ co,
                        const float* __restrict__ vo, unsigned short* __restrict__ out) {
  int i = blockIdx.x * 256 + threadIdx.x;
  int b = i / IND, c = i - b * IND;
  float v;
  if (c < CH) v = mg[b * CH + c];
  else if (c < CH + OUTD) v = co[b * OUTD + (c - CH)];
  else v = vo[b * D_ + (c - CH - OUTD)];
  out[i] = f2b(v);
}

// ---------------- sum 4 fc partial planes + bias + BN + L2 normalize ----------------
__global__ __launch_bounds__(256) void k_bnnorm(const float* __restrict__ x,
    const float* __restrict__ fcb,
    const float* __restrict__ g, const float* __restrict__ bt,
    const float* __restrict__ mn, const float* __restrict__ vr,
    float* __restrict__ out) {
  const int b = blockIdx.x;
  const size_t PL = (size_t)B_ * OUTD;
  __shared__ float red[4];
  float vals[8];
  float ss = 0.f;
#pragma unroll
  for (int i = 0; i < 8; ++i) {
    int c = threadIdx.x + i * 256;
    size_t o = (size_t)b * OUTD + c;
    float xs = x[o] + x[PL + o] + x[2 * PL + o] + x[3 * PL + o] + fcb[c];
    float y = g[c] * (xs - mn[c]) / sqrtf(vr[c] + 1e-5f) + bt[c];
    vals[i] = y;
    ss += y * y;
  }
#pragma unroll
  for (int s2 = 1; s2 < 64; s2 <<= 1) ss += __shfl_xor(ss, s2);
  if ((threadIdx.x & 63) == 0) red[threadIdx.x >> 6] = ss;
  __syncthreads();
  float inv = 1.f / sqrtf(red[0] + red[1] + red[2] + red[3]);
#pragma unroll
  for (int i = 0; i < 8; ++i)
    out[(size_t)b * OUTD + threadIdx.x + i * 256] = vals[i] * inv;
}

extern "C" void kernel_launch(void* const* d_in, const int* in_sizes, int n_in,
                              void* d_out, int out_size, void* d_ws, size_t ws_size,
                              hipStream_t stream) {
  (void)in_sizes; (void)n_in; (void)out_size; (void)ws_size;
  const float* videos = (const float*)d_in[0];
  const float* vorig  = (const float*)d_in[1];
  const int*   lens   = (const int*)d_in[2];
  const float* wihf = (const float*)d_in[4];
  const float* whhf = (const float*)d_in[5];
  const float* bihf = (const float*)d_in[6];
  const float* bhhf = (const float*)d_in[7];
  const float* wihb = (const float*)d_in[8];
  const float* whhb = (const float*)d_in[9];
  const float* bihb = (const float*)d_in[10];
  const float* bhhb = (const float*)d_in[11];
  const float* cw[4] = {(const float*)d_in[12], (const float*)d_in[14],
                        (const float*)d_in[16], (const float*)d_in[18]};
  const float* cb[4] = {(const float*)d_in[13], (const float*)d_in[15],
                        (const float*)d_in[17], (const float*)d_in[19]};
  const float* fcw = (const float*)d_in[20];
  const float* fcb = (const float*)d_in[21];
  const float* bng = (const float*)d_in[22];
  const float* bnb = (const float*)d_in[23];
  const float* bnm = (const float*)d_in[24];
  const float* bnv = (const float*)d_in[25];
  float* out = (float*)d_out;

  char* ws = (char*)d_ws;
  size_t off = 0;
  auto alloc = [&](size_t bytes) -> void* {
    void* p = ws + off;
    off = (off + bytes + 255) & ~(size_t)255;
    return p;
  };
  unsigned int*   flags  = (unsigned int*)alloc(4096);
  unsigned short* xw16   = (unsigned short*)alloc((size_t)2 * B_ * T_ * G3 * 2);  // 100.7 MB
  unsigned short* whh16  = (unsigned short*)alloc((size_t)2 * 3 * H_ * H_ * 2);   // 3.1 MB
  unsigned short* hbuf   = (unsigned short*)alloc((size_t)2 * 2 * B_ * H_ * 2);   // 0.5 MB
  float*          meang  = (float*)alloc((size_t)B_ * CH * 4);
  float*          conout = (float*)alloc((size_t)B_ * OUTD * 4);
  unsigned short* feats  = (unsigned short*)alloc((size_t)B_ * IND * 2);
  float*          fcpart = (float*)alloc((size_t)4 * B_ * OUTD * 4);              // 4.2 MB
  unsigned short* wihcat = (unsigned short*)alloc((size_t)2 * G3 * D_ * 2);       // 12.6 MB
  unsigned short* cw16   = (unsigned short*)alloc((size_t)KC * 14 * CH * 2);
  unsigned short* vid16  = (unsigned short*)alloc((size_t)B_ * T_ * D_ * 2);      // 67.1 MB
  float*          biascat= (float*)alloc(2 * G3 * 4);
  float*          cbcat  = (float*)alloc(4 * KC * 4);
  // vid16 is dead after the xw GEMM; xpad (44.0 MB) + fcT (21.0 MB) alias it.
  unsigned short* xpad = vid16;
  unsigned short* fcT  = vid16 + (size_t)B_ * TP * CH;
  // total ws usage ~200 MB

  hipMemsetAsync(flags, 0, 4096, stream);
  hipMemsetAsync(conout, 0, (size_t)B_ * OUTD * 4, stream);
  hipMemcpyAsync(biascat,      bihf, G3 * 4, hipMemcpyDeviceToDevice, stream);
  hipMemcpyAsync(biascat + G3, bihb, G3 * 4, hipMemcpyDeviceToDevice, stream);
  for (int i = 0; i < 4; ++i)
    hipMemcpyAsync(cbcat + i * KC, cb[i], KC * 4, hipMemcpyDeviceToDevice, stream);

  // pre-convert all GEMM operands to bf16
  k_cvt<<<2048, 256, 0, stream>>>(videos, vid16, B_ * T_ * D_ / 4);
  k_cvt<<<512, 256, 0, stream>>>(wihf, wihcat, G3 * D_ / 4);
  k_cvt<<<512, 256, 0, stream>>>(wihb, wihcat + (size_t)G3 * D_, G3 * D_ / 4);
  k_cvt<<<768, 256, 0, stream>>>(whhf, whh16, 3 * H_ * H_ / 4);
  k_cvt<<<768, 256, 0, stream>>>(whhb, whh16 + (size_t)3 * H_ * H_, 3 * H_ * H_ / 4);
  {
    size_t cwoff = 0;
    for (int i = 0; i < 4; ++i) {
      int w = i + 2;
      int n = KC * w * CH;
      k_cvt<<<256, 256, 0, stream>>>(cw[i], cw16 + cwoff, n / 4);
      cwoff += (size_t)n;
    }
  }

  // merged xw GEMM: [16384 x 3072 x 2048], split-N store into [2][B][T][1536]
  k_gemm<2, 1><<<dim3(128, 24), 256, 0, stream>>>(vid16, wihcat, biascat, xw16, D_, D_, 0, 0);

  // vid16 now dead: init aliased xpad + fcT
  hipMemsetAsync(xpad, 0, (size_t)B_ * TP * CH * 2, stream);
  k_tcvt<<<dim3(64, 160), 256, 0, stream>>>(fcw, fcT);

  // recurrent scan: remap + incremental addressing + flag barrier
  k_scan<<<dim3(32), dim3(512), 0, stream>>>(whh16, bhhf, bhhb, xw16, lens,
                                             hbuf, xpad, meang, flags);

  // all 4 convs in ONE launch (z = conv index), fused relu+bias+time-max
  k_gemm<1, 0><<<dim3(144, 4, 4), 256, 0, stream>>>(xpad, cw16, cbcat, conout, 0, 0, OUTD, 0);

  k_feats<<<2560, 256, 0, stream>>>(meang, conout, vorig, feats);
  // fc split-K x4 into partial planes (deterministic; summed in k_bnnorm)
  k_gemm<3, 0><<<dim3(1, 16, 4), 256, 0, stream>>>(feats, fcT, fcb, fcpart,
                                                   IND / 4, IND, OUTD, IND);
  k_bnnorm<<<B_, 256, 0, stream>>>(fcpart, fcb, bng, bnb, bnm, bnv, out);
}

// Round 16
// 1785.709 us; speedup vs baseline: 1.2314x; 1.2314x over previous
//
#include <hip/hip_runtime.h>
#include <stdint.h>

#define B_   128
#define T_   128
#define D_   2048
#define H_   512
#define G3   1536
#define CH   1024
#define KC   512
#define OUTD 2048
#define IND  5120
#define TP   168
#define MPAD 144

typedef short vb8 __attribute__((ext_vector_type(8)));
typedef float v4f __attribute__((ext_vector_type(4)));

__device__ __forceinline__ unsigned short f2b(float f) {
  unsigned u = __float_as_uint(f);
  u = (u + 0x7FFFu + ((u >> 16) & 1u)) >> 16;
  return (unsigned short)u;
}
__device__ __forceinline__ float b2f(unsigned short u) {
  return __uint_as_float((unsigned)u << 16);
}

__device__ __forceinline__ void gl16(const unsigned short* g, unsigned short* l) {
  __builtin_amdgcn_global_load_lds(
      (const __attribute__((address_space(1))) void*)g,
      (__attribute__((address_space(3))) void*)l, 16, 0, 0);
}

// ---------------- f32 -> bf16 elementwise ----------------
__global__ void k_cvt(const float* __restrict__ in, unsigned short* __restrict__ out, int n4) {
  int stride = gridDim.x * blockDim.x;
  for (int i = blockIdx.x * blockDim.x + threadIdx.x; i < n4; i += stride) {
    float4 v = reinterpret_cast<const float4*>(in)[i];
    ushort4 o;
    o.x = f2b(v.x); o.y = f2b(v.y); o.z = f2b(v.z); o.w = f2b(v.w);
    reinterpret_cast<ushort4*>(out)[i] = o;
  }
}

// ---------------- fc_w [5120][2048] f32 -> [2048][5120] bf16 ----------------
__global__ void k_tcvt(const float* __restrict__ in, unsigned short* __restrict__ out) {
  __shared__ float tile[32][33];
  const int tx = threadIdx.x & 31;
  const int ty = threadIdx.x >> 5; // 0..7
  const int n0 = blockIdx.x * 32;
  const int k0 = blockIdx.y * 32;
#pragma unroll
  for (int i = 0; i < 4; ++i)
    tile[ty + 8 * i][tx] = in[(size_t)(k0 + ty + 8 * i) * OUTD + n0 + tx];
  __syncthreads();
#pragma unroll
  for (int i = 0; i < 4; ++i)
    out[(size_t)(n0 + ty + 8 * i) * IND + k0 + tx] = f2b(tile[tx][ty + 8 * i]);
}

// ---------------- bf16 MFMA GEMM, BK=64, global_load_lds staging ----------------
// C[m][n] = sum_k A[m][k] * Bm[n][k]  (+bias[n])
// K-tile = 64, two independent [128][32] LDS half-tiles per operand.
// EPI==0: linear store (CB: 1=bf16, 0=f32).
// EPI==1: merged conv epilogue (z=conv idx; relu + max over tau, atomicMax).
// EPI==2: merged-xw store: col<1536 -> fwd plane, else bwd plane (bf16).
// EPI==3: fc split-K: z=K-chunk; store raw acc to plane z (f32, no bias).
template<int EPI, int CB>
__global__ __launch_bounds__(256) void k_gemm(
    const unsigned short* __restrict__ A,
    const unsigned short* __restrict__ Bm,
    const float* __restrict__ bias,
    void* __restrict__ Cv,
    int K, int lda, int ldc, int convw)
{
  __shared__ unsigned short sA[2 * 128 * 32];   // halves at +0, +4096
  __shared__ unsigned short sB[2 * 128 * 32];
  float*          C32 = (float*)Cv;
  unsigned short* C16 = (unsigned short*)Cv;

  const int m0 = blockIdx.x * 128;
  const int n0 = blockIdx.y * 128;
  const int cz = blockIdx.z;

  // per-z parameters for merged conv / split-K fc
  int K_ = K;
  int w_ = convw;
  int koff = 0;
  const unsigned short* Bm_ = Bm;
  const float* bias_ = bias;
  if (EPI == 1) {
    constexpr int cum[4] = {0, 2, 5, 9};
    w_   = cz + 2;
    K_   = w_ * CH;
    Bm_  = Bm + (size_t)cum[cz] * KC * CH;
    bias_ = bias + cz * KC;
  } else if (EPI == 3) {
    koff = cz * K;          // K = chunk size; convw = B row stride (full K)
  }
  const int bstride = (EPI == 3) ? convw : K_;

  const int tid  = threadIdx.x;
  const int lane = tid & 63;
  const int wv   = tid >> 6;
  const int wr   = wv >> 1;
  const int wc   = wv & 1;

  const unsigned short* ag[2];
  const unsigned short* bg[2];
  unsigned short* al[2];
  unsigned short* bl[2];
#pragma unroll
  for (int q = 0; q < 2; ++q) {
    int c  = wv * 2 + q;
    int r  = c * 16 + (lane >> 2);
    int kc = (lane & 3) * 8;
    long abase;
    if (EPI == 1) {
      int m   = m0 + r;
      int b   = m / MPAD;
      int tau = m - b * MPAD;
      abase = (long)(b * TP + 4 + tau - (w_ - 1)) * CH;
    } else {
      abase = (long)(m0 + r) * lda + koff;
    }
    ag[q] = A + abase + kc;
    bg[q] = Bm_ + (long)(n0 + r) * bstride + kc + koff;
    al[q] = sA + c * 512;
    bl[q] = sB + c * 512;
  }

  v4f acc[4][4] = {};
  const int kq = (lane >> 4) * 8;
  const int fr = lane & 15;

  for (int k0 = 0; k0 < K_; k0 += 64) {
    if (k0) __syncthreads();
#pragma unroll
    for (int q = 0; q < 2; ++q) {
      gl16(ag[q] + k0,      al[q]);          // half 0
      gl16(ag[q] + k0 + 32, al[q] + 4096);   // half 1
      gl16(bg[q] + k0,      bl[q]);
      gl16(bg[q] + k0 + 32, bl[q] + 4096);
    }
    __syncthreads();
#pragma unroll
    for (int kk = 0; kk < 2; ++kk) {
      const int hb = kk * 4096;
      vb8 af[4], bfr[4];
#pragma unroll
      for (int i = 0; i < 4; ++i) {
        af[i]  = *reinterpret_cast<const vb8*>(sA + hb + (wr * 64 + i * 16 + fr) * 32 + kq);
        bfr[i] = *reinterpret_cast<const vb8*>(sB + hb + (wc * 64 + i * 16 + fr) * 32 + kq);
      }
#pragma unroll
      for (int i = 0; i < 4; ++i)
#pragma unroll
        for (int j = 0; j < 4; ++j)
          acc[i][j] = __builtin_amdgcn_mfma_f32_16x16x32_bf16(af[i], bfr[j], acc[i][j], 0, 0, 0);
    }
  }

  const int rl = lane >> 4;
#pragma unroll
  for (int i = 0; i < 4; ++i) {
#pragma unroll
    for (int j = 0; j < 4; ++j) {
      int col = n0 + wc * 64 + j * 16 + fr;
      float bs = (EPI == 3) ? 0.f : bias_[col];
      if (EPI == 0) {
#pragma unroll
        for (int r = 0; r < 4; ++r) {
          int m = m0 + wr * 64 + i * 16 + rl * 4 + r;
          float v = acc[i][j][r] + bs;
          if (CB) C16[(long)m * ldc + col] = f2b(v);
          else    C32[(long)m * ldc + col] = v;
        }
      } else if (EPI == 2) {
        const int dirb = col >= G3;
        const int xcol = col - dirb * G3;
        unsigned short* base = C16 + (size_t)dirb * ((size_t)B_ * T_ * G3);
#pragma unroll
        for (int r = 0; r < 4; ++r) {
          int m = m0 + wr * 64 + i * 16 + rl * 4 + r;
          base[(long)m * G3 + xcol] = f2b(acc[i][j][r] + bs);
        }
      } else if (EPI == 3) {
#pragma unroll
        for (int r = 0; r < 4; ++r) {
          int m = m0 + wr * 64 + i * 16 + rl * 4 + r;
          C32[(size_t)cz * (B_ * OUTD) + (long)m * ldc + col] = acc[i][j][r];
        }
      } else {
        int mf = m0 + wr * 64 + i * 16;   // 16 | 144 so single b per fragment
        int b  = mf / MPAD;
        int tf = mf - b * MPAD;
        float mx = 0.f;
#pragma unroll
        for (int r = 0; r < 4; ++r) {
          int tau = tf + rl * 4 + r;
          float v = acc[i][j][r] + bs;
          v = v > 0.f ? v : 0.f;
          if (tau < T_ + w_ - 1) mx = v > mx ? v : mx;
        }
        mx = fmaxf(mx, __shfl_xor(mx, 16));
        mx = fmaxf(mx, __shfl_xor(mx, 32));
        if (rl == 0 && tf < T_ + w_ - 1)
          atomicMax(reinterpret_cast<int*>(C32 + (long)b * ldc + cz * KC + col),
                    __float_as_int(mx));
      }
    }
  }
}

// ---------------- persistent bidirectional GRU scan (r14 geometry + incr. addr) ----------------
// 32 WGs x 512 thr (16 per direction), each owns 32 hidden units for ALL 128 batches.
// W_hh slice (96 rows x 512) in LDS, XOR-swizzled, loaded once. Wave wv owns the
// 16-batch M-tile [wv*16, wv*16+16) x all 6 N-tiles -> 96 MFMA/wave/step, ONE
// global h A-load per ks (r14-proven; remap with 2 A-loads regressed in r7/r15).
// ONLY change vs r14: xw/xpad offsets live in registers, advanced by +-G3/+-CH.
// Flag barrier: release fence + per-WG flag store, 16-lane parallel poll, one
// acquire fence. xw prefetched pre-barrier (drains during the spin).
__global__ __launch_bounds__(512) void k_scan(
    const unsigned short* __restrict__ whh16,   // [2][1536][512] bf16
    const float* __restrict__ bhhf, const float* __restrict__ bhhb,
    const unsigned short* __restrict__ xw,      // [2][B][T][1536] bf16
    const int* __restrict__ lengths,
    unsigned short* __restrict__ hbuf,          // [2][2][128][512] bf16
    unsigned short* __restrict__ xpad,
    float* __restrict__ meang,
    unsigned int* __restrict__ flags)           // [2][16] flags, 64B apart
{
  __shared__ unsigned short sw[96 * 512];       // 96 KB, XOR-swizzled rows
  const int wg   = blockIdx.x;                  // 0..31
  const int dir  = wg >> 4;
  const int u0   = (wg & 15) * 32;
  const int tid  = threadIdx.x;                 // 0..511
  const int lane = tid & 63;
  const int wv   = tid >> 6;                    // 0..7 = M-tile
  const int fr   = lane & 15;
  const int rl   = lane >> 4;
  const int kq   = rl * 8;

  const unsigned short* Wd  = whh16 + (size_t)dir * (3 * H_ * H_);
  const float*          bhh = dir ? bhhb : bhhf;
  const unsigned short* xwd = xw + (size_t)dir * ((size_t)B_ * T_ * G3);
  unsigned short* hb = hbuf + dir * (2 * B_ * H_);
  unsigned int* myflags = flags + dir * 16 * 16;  // 16 flags, 64B apart

  // stage W slice: LDS row q = g*32+du  <->  W row g*512 + u0 + du ; swizzle ^((q&7)<<4)
  for (int i = tid; i < 96 * 64; i += 512) {
    int row  = i >> 6;
    int slot = i & 63;
    const unsigned short* src = Wd + (size_t)((row >> 5) * H_ + u0 + (row & 31)) * H_ + slot * 8;
    *reinterpret_cast<vb8*>((char*)sw + ((row * 1024 + slot * 16) ^ ((row & 7) << 4))) =
        *reinterpret_cast<const vb8*>(src);
  }
  __syncthreads();

  const int t0    = dir ? (T_ - 1) : 0;
  const int xstep = dir ? -G3 : G3;             // xw offset delta per step
  const int pstep = dir ? -CH : CH;             // xpad offset delta per step

  int mylen[4];
#pragma unroll
  for (int r = 0; r < 4; ++r) mylen[r] = lengths[wv * 16 + rl * 4 + r];

  float bh[3][2];
#pragma unroll
  for (int g = 0; g < 3; ++g)
#pragma unroll
    for (int j = 0; j < 2; ++j) bh[g][j] = bhh[g * H_ + u0 + j * 16 + fr];

  // register-resident offsets, advanced incrementally each step
  int hoff[2][4], poff[2][4];
#pragma unroll
  for (int j = 0; j < 2; ++j)
#pragma unroll
    for (int r = 0; r < 4; ++r) {
      const int b = wv * 16 + rl * 4 + r;
      const int u = u0 + j * 16 + fr;
      hoff[j][r] = b * H_ + u;
      poff[j][r] = (b * TP + 4 + t0) * CH + dir * H_ + u;
    }
  int xoff[3][2][4];
#pragma unroll
  for (int g = 0; g < 3; ++g)
#pragma unroll
    for (int j = 0; j < 2; ++j)
#pragma unroll
      for (int r = 0; r < 4; ++r)
        xoff[g][j][r] = ((wv * 16 + rl * 4 + r) * T_ + t0) * G3 + g * H_ + u0 + j * 16 + fr;
  const int abase = (wv * 16 + fr) * H_ + kq;

  float hst[8], macc[8];
#pragma unroll
  for (int i = 0; i < 8; ++i) { hst[i] = 0.f; macc[i] = 0.f; }

  // step-0 xw gates
  unsigned short uxw[3][2][4];
#pragma unroll
  for (int g = 0; g < 3; ++g)
#pragma unroll
    for (int j = 0; j < 2; ++j)
#pragma unroll
      for (int r = 0; r < 4; ++r)
        uxw[g][j][r] = xwd[xoff[g][j][r]];

  for (int s = 0; s < T_; ++s) {
    const int t = dir ? (T_ - 1 - s) : s;

    v4f acc[3][2] = {};
    if (s > 0) {
      const unsigned short* arow = hb + ((s - 1) & 1) * (B_ * H_) + abase;
#pragma unroll 4
      for (int ks = 0; ks < 16; ++ks) {
        vb8 a = *reinterpret_cast<const vb8*>(arow + ks * 32);
#pragma unroll
        for (int g = 0; g < 3; ++g)
#pragma unroll
          for (int j = 0; j < 2; ++j) {
            vb8 wf = *reinterpret_cast<const vb8*>(
                (const char*)sw +
                (((g * 32 + j * 16 + fr) * 1024 + ks * 64 + rl * 16) ^ ((fr & 7) << 4)));
            acc[g][j] = __builtin_amdgcn_mfma_f32_16x16x32_bf16(a, wf, acc[g][j], 0, 0, 0);
          }
      }
    }

    unsigned short* hc = hb + (s & 1) * (B_ * H_);
#pragma unroll
    for (int j = 0; j < 2; ++j)
#pragma unroll
      for (int r = 0; r < 4; ++r) {
        const int idx = j * 4 + r;
        float xr = b2f(uxw[0][j][r]), xz = b2f(uxw[1][j][r]), xn = b2f(uxw[2][j][r]);
        float hr = acc[0][j][r] + bh[0][j];
        float hz = acc[1][j][r] + bh[1][j];
        float hn = acc[2][j][r] + bh[2][j];
        float rr = 1.f / (1.f + __expf(-(xr + hr)));
        float z  = 1.f / (1.f + __expf(-(xz + hz)));
        float ax = xn + rr * hn;
        float n  = 2.f / (1.f + __expf(-2.f * ax)) - 1.f;
        float h  = (1.f - z) * n + z * hst[idx];
        hst[idx] = h;
        hc[hoff[j][r]] = f2b(h);
        if (t < mylen[r]) {
          xpad[poff[j][r]] = f2b(h);
          macc[idx] += h;
        }
        poff[j][r] += pstep;
      }

    if (s < T_ - 1) {
      // prefetch next step's xw via incremental offsets (drains during spin)
#pragma unroll
      for (int g = 0; g < 3; ++g)
#pragma unroll
        for (int j = 0; j < 2; ++j)
#pragma unroll
          for (int r = 0; r < 4; ++r) {
            xoff[g][j][r] += xstep;
            uxw[g][j][r] = xwd[xoff[g][j][r]];
          }
      __syncthreads();                 // all waves' h-stores drained to L2
      if (tid == 0) {
        __builtin_amdgcn_fence(__ATOMIC_RELEASE, "agent");   // wbL2: publish h
        __hip_atomic_store(&myflags[(wg & 15) * 16], (unsigned)(s + 1),
                           __ATOMIC_RELAXED, __HIP_MEMORY_SCOPE_AGENT);
      }
      if (tid < 16) {                  // 16 lanes poll 16 flags in parallel
        while (__hip_atomic_load(&myflags[tid * 16], __ATOMIC_RELAXED,
                                 __HIP_MEMORY_SCOPE_AGENT) < (unsigned)(s + 1))
          __builtin_amdgcn_s_sleep(1);
      }
      if (tid == 0)
        __builtin_amdgcn_fence(__ATOMIC_ACQUIRE, "agent");   // one L1/L2 invalidate
      __syncthreads();
    }
  }

#pragma unroll
  for (int j = 0; j < 2; ++j)
#pragma unroll
    for (int r = 0; r < 4; ++r)
      meang[(size_t)(wv * 16 + rl * 4 + r) * CH + dir * H_ + u0 + j * 16 + fr] =
          macc[j * 4 + r] / (float)mylen[r];
}

// ---------------- feats assembly [128][5120] bf16 ----------------
__global__ void k_feats(const float* __restrict__ mg, const float* __restrict__ co,
                        const float* __restrict__ vo, unsigned short* __restrict__ out) {
  int i = blockIdx.x * 256 + threadIdx.x;
  int b = i / IND, c = i - b * IND;
  float v;
  if (c < CH) v = mg[b * CH + c];
  else if (c < CH + OUTD) v = co[b * OUTD + (c - CH)];
  else v = vo[b * D_ + (c - CH - OUTD)];
  out[i] = f2b(v);
}

// ---------------- sum 4 fc partial planes + bias + BN + L2 normalize ----------------
__global__ __launch_bounds__(256) void k_bnnorm(const float* __restrict__ x,
    const float* __restrict__ fcb,
    const float* __restrict__ g, const float* __restrict__ bt,
    const float* __restrict__ mn, const float* __restrict__ vr,
    float* __restrict__ out) {
  const int b = blockIdx.x;
  const size_t PL = (size_t)B_ * OUTD;
  __shared__ float red[4];
  float vals[8];
  float ss = 0.f;
#pragma unroll
  for (int i = 0; i < 8; ++i) {
    int c = threadIdx.x + i * 256;
    size_t o = (size_t)b * OUTD + c;
    float xs = x[o] + x[PL + o] + x[2 * PL + o] + x[3 * PL + o] + fcb[c];
    float y = g[c] * (xs - mn[c]) / sqrtf(vr[c] + 1e-5f) + bt[c];
    vals[i] = y;
    ss += y * y;
  }
#pragma unroll
  for (int s2 = 1; s2 < 64; s2 <<= 1) ss += __shfl_xor(ss, s2);
  if ((threadIdx.x & 63) == 0) red[threadIdx.x >> 6] = ss;
  __syncthreads();
  float inv = 1.f / sqrtf(red[0] + red[1] + red[2] + red[3]);
#pragma unroll
  for (int i = 0; i < 8; ++i)
    out[(size_t)b * OUTD + threadIdx.x + i * 256] = vals[i] * inv;
}

extern "C" void kernel_launch(void* const* d_in, const int* in_sizes, int n_in,
                              void* d_out, int out_size, void* d_ws, size_t ws_size,
                              hipStream_t stream) {
  (void)in_sizes; (void)n_in; (void)out_size; (void)ws_size;
  const float* videos = (const float*)d_in[0];
  const float* vorig  = (const float*)d_in[1];
  const int*   lens   = (const int*)d_in[2];
  const float* wihf = (const float*)d_in[4];
  const float* whhf = (const float*)d_in[5];
  const float* bihf = (const float*)d_in[6];
  const float* bhhf = (const float*)d_in[7];
  const float* wihb = (const float*)d_in[8];
  const float* whhb = (const float*)d_in[9];
  const float* bihb = (const float*)d_in[10];
  const float* bhhb = (const float*)d_in[11];
  const float* cw[4] = {(const float*)d_in[12], (const float*)d_in[14],
                        (const float*)d_in[16], (const float*)d_in[18]};
  const float* cb[4] = {(const float*)d_in[13], (const float*)d_in[15],
                        (const float*)d_in[17], (const float*)d_in[19]};
  const float* fcw = (const float*)d_in[20];
  const float* fcb = (const float*)d_in[21];
  const float* bng = (const float*)d_in[22];
  const float* bnb = (const float*)d_in[23];
  const float* bnm = (const float*)d_in[24];
  const float* bnv = (const float*)d_in[25];
  float* out = (float*)d_out;

  char* ws = (char*)d_ws;
  size_t off = 0;
  auto alloc = [&](size_t bytes) -> void* {
    void* p = ws + off;
    off = (off + bytes + 255) & ~(size_t)255;
    return p;
  };
  unsigned int*   flags  = (unsigned int*)alloc(4096);
  unsigned short* xw16   = (unsigned short*)alloc((size_t)2 * B_ * T_ * G3 * 2);  // 100.7 MB
  unsigned short* whh16  = (unsigned short*)alloc((size_t)2 * 3 * H_ * H_ * 2);   // 3.1 MB
  unsigned short* hbuf   = (unsigned short*)alloc((size_t)2 * 2 * B_ * H_ * 2);   // 0.5 MB
  float*          meang  = (float*)alloc((size_t)B_ * CH * 4);
  float*          conout = (float*)alloc((size_t)B_ * OUTD * 4);
  unsigned short* feats  = (unsigned short*)alloc((size_t)B_ * IND * 2);
  float*          fcpart = (float*)alloc((size_t)4 * B_ * OUTD * 4);              // 4.2 MB
  unsigned short* wihcat = (unsigned short*)alloc((size_t)2 * G3 * D_ * 2);       // 12.6 MB
  unsigned short* cw16   = (unsigned short*)alloc((size_t)KC * 14 * CH * 2);
  unsigned short* vid16  = (unsigned short*)alloc((size_t)B_ * T_ * D_ * 2);      // 67.1 MB
  float*          biascat= (float*)alloc(2 * G3 * 4);
  float*          cbcat  = (float*)alloc(4 * KC * 4);
  // vid16 is dead after the xw GEMM; xpad (44.0 MB) + fcT (21.0 MB) alias it.
  unsigned short* xpad = vid16;
  unsigned short* fcT  = vid16 + (size_t)B_ * TP * CH;
  // total ws usage ~200 MB

  hipMemsetAsync(flags, 0, 4096, stream);
  hipMemsetAsync(conout, 0, (size_t)B_ * OUTD * 4, stream);
  hipMemcpyAsync(biascat,      bihf, G3 * 4, hipMemcpyDeviceToDevice, stream);
  hipMemcpyAsync(biascat + G3, bihb, G3 * 4, hipMemcpyDeviceToDevice, stream);
  for (int i = 0; i < 4; ++i)
    hipMemcpyAsync(cbcat + i * KC, cb[i], KC * 4, hipMemcpyDeviceToDevice, stream);

  // pre-convert all GEMM operands to bf16
  k_cvt<<<2048, 256, 0, stream>>>(videos, vid16, B_ * T_ * D_ / 4);
  k_cvt<<<512, 256, 0, stream>>>(wihf, wihcat, G3 * D_ / 4);
  k_cvt<<<512, 256, 0, stream>>>(wihb, wihcat + (size_t)G3 * D_, G3 * D_ / 4);
  k_cvt<<<768, 256, 0, stream>>>(whhf, whh16, 3 * H_ * H_ / 4);
  k_cvt<<<768, 256, 0, stream>>>(whhb, whh16 + (size_t)3 * H_ * H_, 3 * H_ * H_ / 4);
  {
    size_t cwoff = 0;
    for (int i = 0; i < 4; ++i) {
      int w = i + 2;
      int n = KC * w * CH;
      k_cvt<<<256, 256, 0, stream>>>(cw[i], cw16 + cwoff, n / 4);
      cwoff += (size_t)n;
    }
  }

  // merged xw GEMM: [16384 x 3072 x 2048], split-N store into [2][B][T][1536]
  k_gemm<2, 1><<<dim3(128, 24), 256, 0, stream>>>(vid16, wihcat, biascat, xw16, D_, D_, 0, 0);

  // vid16 now dead: init aliased xpad + fcT
  hipMemsetAsync(xpad, 0, (size_t)B_ * TP * CH * 2, stream);
  k_tcvt<<<dim3(64, 160), 256, 0, stream>>>(fcw, fcT);

  // recurrent scan: r14 geometry + incremental addressing + flag barrier
  k_scan<<<dim3(32), dim3(512), 0, stream>>>(whh16, bhhf, bhhb, xw16, lens,
                                             hbuf, xpad, meang, flags);

  // all 4 convs in ONE launch (z = conv index), fused relu+bias+time-max
  k_gemm<1, 0><<<dim3(144, 4, 4), 256, 0, stream>>>(xpad, cw16, cbcat, conout, 0, 0, OUTD, 0);

  k_feats<<<2560, 256, 0, stream>>>(meang, conout, vorig, feats);
  // fc split-K x4 into partial planes (deterministic; summed in k_bnnorm)
  k_gemm<3, 0><<<dim3(1, 16, 4), 256, 0, stream>>>(feats, fcT, fcb, fcpart,
                                                   IND / 4, IND, OUTD, IND);
  k_bnnorm<<<B_, 256, 0, stream>>>(fcpart, fcb, bng, bnb, bnm, bnv, out);
}

// Round 17
// 1712.953 us; speedup vs baseline: 1.2837x; 1.0425x over previous
//
#include <hip/hip_runtime.h>
#include <stdint.h>

#define B_   128
#define T_   128
#define D_   2048
#define H_   512
#define G3   1536
#define CH   1024
#define KC   512
#define OUTD 2048
#define IND  5120
#define TP   168
#define MPAD 144

typedef short vb8 __attribute__((ext_vector_type(8)));
typedef float v4f __attribute__((ext_vector_type(4)));

__device__ __forceinline__ unsigned short f2b(float f) {
  unsigned u = __float_as_uint(f);
  u = (u + 0x7FFFu + ((u >> 16) & 1u)) >> 16;
  return (unsigned short)u;
}
__device__ __forceinline__ float b2f(unsigned short u) {
  return __uint_as_float((unsigned)u << 16);
}

__device__ __forceinline__ void gl16(const unsigned short* g, unsigned short* l) {
  __builtin_amdgcn_global_load_lds(
      (const __attribute__((address_space(1))) void*)g,
      (__attribute__((address_space(3))) void*)l, 16, 0, 0);
}

// ---------------- batched f32 -> bf16 conversion (9 segments, one launch) ----------------
struct CvtArgs {
  const float* src[9];
  unsigned short* dst[9];
  int cum[10];   // vec4 cumsum; cum[9] = total
};

__global__ void k_cvtall(CvtArgs a) {
  const int stride = gridDim.x * blockDim.x;
  for (int i = blockIdx.x * blockDim.x + threadIdx.x; i < a.cum[9]; i += stride) {
    int s = 0;
#pragma unroll
    for (int q = 1; q < 9; ++q) s += (i >= a.cum[q]);
    const int off = i - a.cum[s];
    float4 v = reinterpret_cast<const float4*>(a.src[s])[off];
    ushort4 o;
    o.x = f2b(v.x); o.y = f2b(v.y); o.z = f2b(v.z); o.w = f2b(v.w);
    reinterpret_cast<ushort4*>(a.dst[s])[off] = o;
  }
}

// ---------------- bias concatenation (replaces 6 tiny D2D copies) ----------------
__global__ void k_bias(const float* __restrict__ bihf, const float* __restrict__ bihb,
                       const float* __restrict__ cb0, const float* __restrict__ cb1,
                       const float* __restrict__ cb2, const float* __restrict__ cb3,
                       float* __restrict__ biascat, float* __restrict__ cbcat) {
  for (int i = threadIdx.x; i < G3; i += 256) {
    biascat[i]      = bihf[i];
    biascat[G3 + i] = bihb[i];
  }
  for (int i = threadIdx.x; i < KC; i += 256) {
    cbcat[i]          = cb0[i];
    cbcat[KC + i]     = cb1[i];
    cbcat[2 * KC + i] = cb2[i];
    cbcat[3 * KC + i] = cb3[i];
  }
}

// ---------------- fc_w [5120][2048] f32 -> [2048][5120] bf16 ----------------
__global__ void k_tcvt(const float* __restrict__ in, unsigned short* __restrict__ out) {
  __shared__ float tile[32][33];
  const int tx = threadIdx.x & 31;
  const int ty = threadIdx.x >> 5; // 0..7
  const int n0 = blockIdx.x * 32;
  const int k0 = blockIdx.y * 32;
#pragma unroll
  for (int i = 0; i < 4; ++i)
    tile[ty + 8 * i][tx] = in[(size_t)(k0 + ty + 8 * i) * OUTD + n0 + tx];
  __syncthreads();
#pragma unroll
  for (int i = 0; i < 4; ++i)
    out[(size_t)(n0 + ty + 8 * i) * IND + k0 + tx] = f2b(tile[tx][ty + 8 * i]);
}

// ---------------- bf16 MFMA GEMM, BK=64, global_load_lds staging ----------------
// C[m][n] = sum_k A[m][k] * Bm[n][k]  (+bias[n])
// K-tile = 64, two independent [128][32] LDS half-tiles per operand.
// EPI==0: linear store (CB: 1=bf16, 0=f32).
// EPI==1: merged conv epilogue (z=conv idx; relu + max over tau, atomicMax).
// EPI==2: merged-xw store: col<1536 -> fwd plane, else bwd plane (bf16).
// EPI==3: fc split-K: z=K-chunk; store raw acc to plane z (f32, no bias).
template<int EPI, int CB>
__global__ __launch_bounds__(256) void k_gemm(
    const unsigned short* __restrict__ A,
    const unsigned short* __restrict__ Bm,
    const float* __restrict__ bias,
    void* __restrict__ Cv,
    int K, int lda, int ldc, int convw)
{
  __shared__ unsigned short sA[2 * 128 * 32];   // halves at +0, +4096
  __shared__ unsigned short sB[2 * 128 * 32];
  float*          C32 = (float*)Cv;
  unsigned short* C16 = (unsigned short*)Cv;

  const int m0 = blockIdx.x * 128;
  const int n0 = blockIdx.y * 128;
  const int cz = blockIdx.z;

  // per-z parameters for merged conv / split-K fc
  int K_ = K;
  int w_ = convw;
  int koff = 0;
  const unsigned short* Bm_ = Bm;
  const float* bias_ = bias;
  if (EPI == 1) {
    constexpr int cum[4] = {0, 2, 5, 9};
    w_   = cz + 2;
    K_   = w_ * CH;
    Bm_  = Bm + (size_t)cum[cz] * KC * CH;
    bias_ = bias + cz * KC;
  } else if (EPI == 3) {
    koff = cz * K;          // K = chunk size; convw = B row stride (full K)
  }
  const int bstride = (EPI == 3) ? convw : K_;

  const int tid  = threadIdx.x;
  const int lane = tid & 63;
  const int wv   = tid >> 6;
  const int wr   = wv >> 1;
  const int wc   = wv & 1;

  const unsigned short* ag[2];
  const unsigned short* bg[2];
  unsigned short* al[2];
  unsigned short* bl[2];
#pragma unroll
  for (int q = 0; q < 2; ++q) {
    int c  = wv * 2 + q;
    int r  = c * 16 + (lane >> 2);
    int kc = (lane & 3) * 8;
    long abase;
    if (EPI == 1) {
      int m   = m0 + r;
      int b   = m / MPAD;
      int tau = m - b * MPAD;
      abase = (long)(b * TP + 4 + tau - (w_ - 1)) * CH;
    } else {
      abase = (long)(m0 + r) * lda + koff;
    }
    ag[q] = A + abase + kc;
    bg[q] = Bm_ + (long)(n0 + r) * bstride + kc + koff;
    al[q] = sA + c * 512;
    bl[q] = sB + c * 512;
  }

  v4f acc[4][4] = {};
  const int kq = (lane >> 4) * 8;
  const int fr = lane & 15;

  for (int k0 = 0; k0 < K_; k0 += 64) {
    if (k0) __syncthreads();
#pragma unroll
    for (int q = 0; q < 2; ++q) {
      gl16(ag[q] + k0,      al[q]);          // half 0
      gl16(ag[q] + k0 + 32, al[q] + 4096);   // half 1
      gl16(bg[q] + k0,      bl[q]);
      gl16(bg[q] + k0 + 32, bl[q] + 4096);
    }
    __syncthreads();
#pragma unroll
    for (int kk = 0; kk < 2; ++kk) {
      const int hb = kk * 4096;
      vb8 af[4], bfr[4];
#pragma unroll
      for (int i = 0; i < 4; ++i) {
        af[i]  = *reinterpret_cast<const vb8*>(sA + hb + (wr * 64 + i * 16 + fr) * 32 + kq);
        bfr[i] = *reinterpret_cast<const vb8*>(sB + hb + (wc * 64 + i * 16 + fr) * 32 + kq);
      }
#pragma unroll
      for (int i = 0; i < 4; ++i)
#pragma unroll
        for (int j = 0; j < 4; ++j)
          acc[i][j] = __builtin_amdgcn_mfma_f32_16x16x32_bf16(af[i], bfr[j], acc[i][j], 0, 0, 0);
    }
  }

  const int rl = lane >> 4;
#pragma unroll
  for (int i = 0; i < 4; ++i) {
#pragma unroll
    for (int j = 0; j < 4; ++j) {
      int col = n0 + wc * 64 + j * 16 + fr;
      float bs = (EPI == 3) ? 0.f : bias_[col];
      if (EPI == 0) {
#pragma unroll
        for (int r = 0; r < 4; ++r) {
          int m = m0 + wr * 64 + i * 16 + rl * 4 + r;
          float v = acc[i][j][r] + bs;
          if (CB) C16[(long)m * ldc + col] = f2b(v);
          else    C32[(long)m * ldc + col] = v;
        }
      } else if (EPI == 2) {
        const int dirb = col >= G3;
        const int xcol = col - dirb * G3;
        unsigned short* base = C16 + (size_t)dirb * ((size_t)B_ * T_ * G3);
#pragma unroll
        for (int r = 0; r < 4; ++r) {
          int m = m0 + wr * 64 + i * 16 + rl * 4 + r;
          base[(long)m * G3 + xcol] = f2b(acc[i][j][r] + bs);
        }
      } else if (EPI == 3) {
#pragma unroll
        for (int r = 0; r < 4; ++r) {
          int m = m0 + wr * 64 + i * 16 + rl * 4 + r;
          C32[(size_t)cz * (B_ * OUTD) + (long)m * ldc + col] = acc[i][j][r];
        }
      } else {
        int mf = m0 + wr * 64 + i * 16;   // 16 | 144 so single b per fragment
        int b  = mf / MPAD;
        int tf = mf - b * MPAD;
        float mx = 0.f;
#pragma unroll
        for (int r = 0; r < 4; ++r) {
          int tau = tf + rl * 4 + r;
          float v = acc[i][j][r] + bs;
          v = v > 0.f ? v : 0.f;
          if (tau < T_ + w_ - 1) mx = v > mx ? v : mx;
        }
        mx = fmaxf(mx, __shfl_xor(mx, 16));
        mx = fmaxf(mx, __shfl_xor(mx, 32));
        if (rl == 0 && tf < T_ + w_ - 1)
          atomicMax(reinterpret_cast<int*>(C32 + (long)b * ldc + cz * KC + col),
                    __float_as_int(mx));
      }
    }
  }
}

// ---------------- persistent bidirectional GRU scan (r14 proven config) ----------------
// 32 WGs x 512 thr (16 per direction), each owns 32 hidden units for ALL 128 batches.
// W_hh slice (96 rows x 512) in LDS, XOR-swizzled, loaded once. Wave wv owns the
// 16-batch M-tile [wv*16, wv*16+16) x all 6 N-tiles -> 96 MFMA/wave/step.
// Flag barrier: release fence + per-WG flag store, 16-lane parallel poll, one
// acquire fence. xw prefetched pre-barrier (drains during the spin).
__global__ __launch_bounds__(512) void k_scan(
    const unsigned short* __restrict__ whh16,   // [2][1536][512] bf16
    const float* __restrict__ bhhf, const float* __restrict__ bhhb,
    const unsigned short* __restrict__ xw,      // [2][B][T][1536] bf16
    const int* __restrict__ lengths,
    unsigned short* __restrict__ hbuf,          // [2][2][128][512] bf16
    unsigned short* __restrict__ xpad,
    float* __restrict__ meang,
    unsigned int* __restrict__ flags)           // [2][16] flags, 64B apart
{
  __shared__ unsigned short sw[96 * 512];       // 96 KB, XOR-swizzled rows
  const int wg   = blockIdx.x;                  // 0..31
  const int dir  = wg >> 4;
  const int u0   = (wg & 15) * 32;
  const int tid  = threadIdx.x;                 // 0..511
  const int lane = tid & 63;
  const int wv   = tid >> 6;                    // 0..7 = M-tile
  const int fr   = lane & 15;
  const int rl   = lane >> 4;
  const int kq   = rl * 8;

  const unsigned short* Wd  = whh16 + (size_t)dir * (3 * H_ * H_);
  const float*          bhh = dir ? bhhb : bhhf;
  const unsigned short* xwd = xw + (size_t)dir * ((size_t)B_ * T_ * G3);
  unsigned short* hb = hbuf + dir * (2 * B_ * H_);
  unsigned int* myflags = flags + dir * 16 * 16;  // 16 flags, 64B apart

  // stage W slice: LDS row q = g*32+du  <->  W row g*512 + u0 + du ; swizzle ^((q&7)<<4)
  for (int i = tid; i < 96 * 64; i += 512) {
    int row  = i >> 6;
    int slot = i & 63;
    const unsigned short* src = Wd + (size_t)((row >> 5) * H_ + u0 + (row & 31)) * H_ + slot * 8;
    *reinterpret_cast<vb8*>((char*)sw + ((row * 1024 + slot * 16) ^ ((row & 7) << 4))) =
        *reinterpret_cast<const vb8*>(src);
  }
  __syncthreads();

  int mylen[4];
#pragma unroll
  for (int r = 0; r < 4; ++r) mylen[r] = lengths[wv * 16 + rl * 4 + r];

  float bh[3][2];
#pragma unroll
  for (int g = 0; g < 3; ++g)
#pragma unroll
    for (int j = 0; j < 2; ++j) bh[g][j] = bhh[g * H_ + u0 + j * 16 + fr];

  float hst[8], macc[8];
#pragma unroll
  for (int i = 0; i < 8; ++i) { hst[i] = 0.f; macc[i] = 0.f; }

  // prefetch step-0 xw gates
  unsigned short uxw[3][2][4];
  {
    const int t0 = dir ? (T_ - 1) : 0;
#pragma unroll
    for (int g = 0; g < 3; ++g)
#pragma unroll
      for (int j = 0; j < 2; ++j)
#pragma unroll
        for (int r = 0; r < 4; ++r)
          uxw[g][j][r] = xwd[((size_t)(wv * 16 + rl * 4 + r) * T_ + t0) * G3 +
                             g * H_ + u0 + j * 16 + fr];
  }

  for (int s = 0; s < T_; ++s) {
    const int t = dir ? (T_ - 1 - s) : s;

    v4f acc[3][2] = {};
    if (s > 0) {
      const unsigned short* arow = hb + ((s - 1) & 1) * (B_ * H_) + (wv * 16 + fr) * H_;
#pragma unroll 4
      for (int ks = 0; ks < 16; ++ks) {
        vb8 a = *reinterpret_cast<const vb8*>(arow + ks * 32 + kq);
#pragma unroll
        for (int g = 0; g < 3; ++g)
#pragma unroll
          for (int j = 0; j < 2; ++j) {
            vb8 wf = *reinterpret_cast<const vb8*>(
                (const char*)sw +
                (((g * 32 + j * 16 + fr) * 1024 + ks * 64 + rl * 16) ^ ((fr & 7) << 4)));
            acc[g][j] = __builtin_amdgcn_mfma_f32_16x16x32_bf16(a, wf, acc[g][j], 0, 0, 0);
          }
      }
    }

    unsigned short* hc = hb + (s & 1) * (B_ * H_);
#pragma unroll
    for (int j = 0; j < 2; ++j)
#pragma unroll
      for (int r = 0; r < 4; ++r) {
        const int idx = j * 4 + r;
        const int b   = wv * 16 + rl * 4 + r;
        const int u   = u0 + j * 16 + fr;
        float xr = b2f(uxw[0][j][r]), xz = b2f(uxw[1][j][r]), xn = b2f(uxw[2][j][r]);
        float hr = acc[0][j][r] + bh[0][j];
        float hz = acc[1][j][r] + bh[1][j];
        float hn = acc[2][j][r] + bh[2][j];
        float rr = 1.f / (1.f + __expf(-(xr + hr)));
        float z  = 1.f / (1.f + __expf(-(xz + hz)));
        float ax = xn + rr * hn;
        float n  = 2.f / (1.f + __expf(-2.f * ax)) - 1.f;
        float h  = (1.f - z) * n + z * hst[idx];
        hst[idx] = h;
        hc[b * H_ + u] = f2b(h);
        if (t < mylen[r]) {
          xpad[((size_t)b * TP + 4 + t) * CH + dir * H_ + u] = f2b(h);
          macc[idx] += h;
        }
      }

    if (s < T_ - 1) {
      // prefetch next step's xw (registers survive the fence)
      const int tn = dir ? (T_ - 2 - s) : (s + 1);
#pragma unroll
      for (int g = 0; g < 3; ++g)
#pragma unroll
        for (int j = 0; j < 2; ++j)
#pragma unroll
          for (int r = 0; r < 4; ++r)
            uxw[g][j][r] = xwd[((size_t)(wv * 16 + rl * 4 + r) * T_ + tn) * G3 +
                               g * H_ + u0 + j * 16 + fr];
      __syncthreads();                 // all waves' h-stores drained to L2
      if (tid == 0) {
        __builtin_amdgcn_fence(__ATOMIC_RELEASE, "agent");   // wbL2: publish h
        __hip_atomic_store(&myflags[(wg & 15) * 16], (unsigned)(s + 1),
                           __ATOMIC_RELAXED, __HIP_MEMORY_SCOPE_AGENT);
      }
      if (tid < 16) {                  // 16 lanes poll 16 flags in parallel
        while (__hip_atomic_load(&myflags[tid * 16], __ATOMIC_RELAXED,
                                 __HIP_MEMORY_SCOPE_AGENT) < (unsigned)(s + 1))
          __builtin_amdgcn_s_sleep(1);
      }
      if (tid == 0)
        __builtin_amdgcn_fence(__ATOMIC_ACQUIRE, "agent");   // one L1/L2 invalidate
      __syncthreads();
    }
  }

#pragma unroll
  for (int j = 0; j < 2; ++j)
#pragma unroll
    for (int r = 0; r < 4; ++r)
      meang[(size_t)(wv * 16 + rl * 4 + r) * CH + dir * H_ + u0 + j * 16 + fr] =
          macc[j * 4 + r] / (float)mylen[r];
}

// ---------------- feats assembly [128][5120] bf16 ----------------
__global__ void k_feats(const float* __restrict__ mg, const float* __restrict__ co,
                        const float* __restrict__ vo, unsigned short* __restrict__ out) {
  int i = blockIdx.x * 256 + threadIdx.x;
  int b = i / IND, c = i - b * IND;
  float v;
  if (c < CH) v = mg[b * CH + c];
  else if (c < CH + OUTD) v = co[b * OUTD + (c - CH)];
  else v = vo[b * D_ + (c - CH - OUTD)];
  out[i] = f2b(v);
}

// ---------------- sum 4 fc partial planes + bias + BN + L2 normalize ----------------
__global__ __launch_bounds__(256) void k_bnnorm(const float* __restrict__ x,
    const float* __restrict__ fcb,
    const float* __restrict__ g, const float* __restrict__ bt,
    const float* __restrict__ mn, const float* __restrict__ vr,
    float* __restrict__ out) {
  const int b = blockIdx.x;
  const size_t PL = (size_t)B_ * OUTD;
  __shared__ float red[4];
  float vals[8];
  float ss = 0.f;
#pragma unroll
  for (int i = 0; i < 8; ++i) {
    int c = threadIdx.x + i * 256;
    size_t o = (size_t)b * OUTD + c;
    float xs = x[o] + x[PL + o] + x[2 * PL + o] + x[3 * PL + o] + fcb[c];
    float y = g[c] * (xs - mn[c]) / sqrtf(vr[c] + 1e-5f) + bt[c];
    vals[i] = y;
    ss += y * y;
  }
#pragma unroll
  for (int s2 = 1; s2 < 64; s2 <<= 1) ss += __shfl_xor(ss, s2);
  if ((threadIdx.x & 63) == 0) red[threadIdx.x >> 6] = ss;
  __syncthreads();
  float inv = 1.f / sqrtf(red[0] + red[1] + red[2] + red[3]);
#pragma unroll
  for (int i = 0; i < 8; ++i)
    out[(size_t)b * OUTD + threadIdx.x + i * 256] = vals[i] * inv;
}

extern "C" void kernel_launch(void* const* d_in, const int* in_sizes, int n_in,
                              void* d_out, int out_size, void* d_ws, size_t ws_size,
                              hipStream_t stream) {
  (void)in_sizes; (void)n_in; (void)out_size; (void)ws_size;
  const float* videos = (const float*)d_in[0];
  const float* vorig  = (const float*)d_in[1];
  const int*   lens   = (const int*)d_in[2];
  const float* wihf = (const float*)d_in[4];
  const float* whhf = (const float*)d_in[5];
  const float* bihf = (const float*)d_in[6];
  const float* bhhf = (const float*)d_in[7];
  const float* wihb = (const float*)d_in[8];
  const float* whhb = (const float*)d_in[9];
  const float* bihb = (const float*)d_in[10];
  const float* bhhb = (const float*)d_in[11];
  const float* cw[4] = {(const float*)d_in[12], (const float*)d_in[14],
                        (const float*)d_in[16], (const float*)d_in[18]};
  const float* cb[4] = {(const float*)d_in[13], (const float*)d_in[15],
                        (const float*)d_in[17], (const float*)d_in[19]};
  const float* fcw = (const float*)d_in[20];
  const float* fcb = (const float*)d_in[21];
  const float* bng = (const float*)d_in[22];
  const float* bnb = (const float*)d_in[23];
  const float* bnm = (const float*)d_in[24];
  const float* bnv = (const float*)d_in[25];
  float* out = (float*)d_out;

  char* ws = (char*)d_ws;
  size_t off = 0;
  auto alloc = [&](size_t bytes) -> void* {
    void* p = ws + off;
    off = (off + bytes + 255) & ~(size_t)255;
    return p;
  };
  unsigned int*   flags  = (unsigned int*)alloc(4096);
  unsigned short* xw16   = (unsigned short*)alloc((size_t)2 * B_ * T_ * G3 * 2);  // 100.7 MB
  unsigned short* whh16  = (unsigned short*)alloc((size_t)2 * 3 * H_ * H_ * 2);   // 3.1 MB
  unsigned short* hbuf   = (unsigned short*)alloc((size_t)2 * 2 * B_ * H_ * 2);   // 0.5 MB
  float*          meang  = (float*)alloc((size_t)B_ * CH * 4);
  float*          conout = (float*)alloc((size_t)B_ * OUTD * 4);
  unsigned short* feats  = (unsigned short*)alloc((size_t)B_ * IND * 2);
  float*          fcpart = (float*)alloc((size_t)4 * B_ * OUTD * 4);              // 4.2 MB
  unsigned short* wihcat = (unsigned short*)alloc((size_t)2 * G3 * D_ * 2);       // 12.6 MB
  unsigned short* cw16   = (unsigned short*)alloc((size_t)KC * 14 * CH * 2);
  unsigned short* vid16  = (unsigned short*)alloc((size_t)B_ * T_ * D_ * 2);      // 67.1 MB
  float*          biascat= (float*)alloc(2 * G3 * 4);
  float*          cbcat  = (float*)alloc(4 * KC * 4);
  // vid16 is dead after the xw GEMM; xpad (44.0 MB) + fcT (21.0 MB) alias it.
  unsigned short* xpad = vid16;
  unsigned short* fcT  = vid16 + (size_t)B_ * TP * CH;
  // total ws usage ~200 MB

  hipMemsetAsync(flags, 0, 4096, stream);
  hipMemsetAsync(conout, 0, (size_t)B_ * OUTD * 4, stream);

  // bias concatenations (one tiny kernel instead of 6 D2D copies)
  k_bias<<<1, 256, 0, stream>>>(bihf, bihb, cb[0], cb[1], cb[2], cb[3], biascat, cbcat);

  // all f32->bf16 conversions in ONE launch (9 segments)
  {
    CvtArgs a;
    a.src[0] = videos; a.dst[0] = vid16;
    a.src[1] = wihf;   a.dst[1] = wihcat;
    a.src[2] = wihb;   a.dst[2] = wihcat + (size_t)G3 * D_;
    a.src[3] = whhf;   a.dst[3] = whh16;
    a.src[4] = whhb;   a.dst[4] = whh16 + (size_t)3 * H_ * H_;
    size_t cwoff = 0;
    for (int i = 0; i < 4; ++i) {
      a.src[5 + i] = cw[i];
      a.dst[5 + i] = cw16 + cwoff;
      cwoff += (size_t)KC * (i + 2) * CH;
    }
    int n4[9] = {B_ * T_ * D_ / 4, G3 * D_ / 4, G3 * D_ / 4,
                 3 * H_ * H_ / 4, 3 * H_ * H_ / 4,
                 KC * 2 * CH / 4, KC * 3 * CH / 4, KC * 4 * CH / 4, KC * 5 * CH / 4};
    a.cum[0] = 0;
    for (int i = 0; i < 9; ++i) a.cum[i + 1] = a.cum[i] + n4[i];
    k_cvtall<<<2048, 256, 0, stream>>>(a);
  }

  // merged xw GEMM: [16384 x 3072 x 2048], split-N store into [2][B][T][1536]
  k_gemm<2, 1><<<dim3(128, 24), 256, 0, stream>>>(vid16, wihcat, biascat, xw16, D_, D_, 0, 0);

  // vid16 now dead: init aliased xpad + fcT
  hipMemsetAsync(xpad, 0, (size_t)B_ * TP * CH * 2, stream);
  k_tcvt<<<dim3(64, 160), 256, 0, stream>>>(fcw, fcT);

  // recurrent scan: r14 proven config (flag barrier)
  k_scan<<<dim3(32), dim3(512), 0, stream>>>(whh16, bhhf, bhhb, xw16, lens,
                                             hbuf, xpad, meang, flags);

  // all 4 convs in ONE launch (z = conv index), fused relu+bias+time-max
  k_gemm<1, 0><<<dim3(144, 4, 4), 256, 0, stream>>>(xpad, cw16, cbcat, conout, 0, 0, OUTD, 0);

  k_feats<<<2560, 256, 0, stream>>>(meang, conout, vorig, feats);
  // fc split-K x4 into partial planes (deterministic; summed in k_bnnorm)
  k_gemm<3, 0><<<dim3(1, 16, 4), 256, 0, stream>>>(feats, fcT, fcb, fcpart,
                                                   IND / 4, IND, OUTD, IND);
  k_bnnorm<<<B_, 256, 0, stream>>>(fcpart, fcb, bng, bnb, bnm, bnv, out);
}